// Round 2
// baseline (49.858 us; speedup 1.0000x reference)
//
#include <hip/hip_runtime.h>

// kp_loss: result = sum_{b,k} exp(-||out[b,k]-tgt[b,k]||^2 / 2) / B
// B=8192, K=2048 -> 16.7M keypoints, 268 MB input, scalar output.
// Inputs are L3-resident on timed replays (268 MB vs 256 MB L3, FETCH~0),
// so the limit is L3-stream latency/BW, not HBM. Unroll x4 for MLP.

#define KP_B 8192

__global__ __launch_bounds__(256) void kp_partial_kernel(
    const float4* __restrict__ out4,
    const float4* __restrict__ tgt4,
    float* __restrict__ partial,
    int n4)
{
    int tid = blockIdx.x * blockDim.x + threadIdx.x;
    int stride = gridDim.x * blockDim.x;

    float acc0 = 0.0f, acc1 = 0.0f, acc2 = 0.0f, acc3 = 0.0f;

    int i = tid;
    // main: 4 grid-stride steps per loop -> 8 independent float4 loads in flight
    for (; i + 3 * stride < n4; i += 4 * stride) {
        float4 o0 = out4[i];
        float4 t0 = tgt4[i];
        float4 o1 = out4[i + stride];
        float4 t1 = tgt4[i + stride];
        float4 o2 = out4[i + 2 * stride];
        float4 t2 = tgt4[i + 2 * stride];
        float4 o3 = out4[i + 3 * stride];
        float4 t3 = tgt4[i + 3 * stride];

        {
            float dx0 = o0.x - t0.x, dy0 = o0.y - t0.y;
            float dx1 = o0.z - t0.z, dy1 = o0.w - t0.w;
            acc0 += __expf(-0.5f * (dx0 * dx0 + dy0 * dy0));
            acc0 += __expf(-0.5f * (dx1 * dx1 + dy1 * dy1));
        }
        {
            float dx0 = o1.x - t1.x, dy0 = o1.y - t1.y;
            float dx1 = o1.z - t1.z, dy1 = o1.w - t1.w;
            acc1 += __expf(-0.5f * (dx0 * dx0 + dy0 * dy0));
            acc1 += __expf(-0.5f * (dx1 * dx1 + dy1 * dy1));
        }
        {
            float dx0 = o2.x - t2.x, dy0 = o2.y - t2.y;
            float dx1 = o2.z - t2.z, dy1 = o2.w - t2.w;
            acc2 += __expf(-0.5f * (dx0 * dx0 + dy0 * dy0));
            acc2 += __expf(-0.5f * (dx1 * dx1 + dy1 * dy1));
        }
        {
            float dx0 = o3.x - t3.x, dy0 = o3.y - t3.y;
            float dx1 = o3.z - t3.z, dy1 = o3.w - t3.w;
            acc3 += __expf(-0.5f * (dx0 * dx0 + dy0 * dy0));
            acc3 += __expf(-0.5f * (dx1 * dx1 + dy1 * dy1));
        }
    }
    // remainder
    for (; i < n4; i += stride) {
        float4 o = out4[i];
        float4 t = tgt4[i];
        float dx0 = o.x - t.x, dy0 = o.y - t.y;
        float dx1 = o.z - t.z, dy1 = o.w - t.w;
        acc0 += __expf(-0.5f * (dx0 * dx0 + dy0 * dy0));
        acc0 += __expf(-0.5f * (dx1 * dx1 + dy1 * dy1));
    }

    float acc = (acc0 + acc1) + (acc2 + acc3);

    // wave-64 butterfly reduce
    #pragma unroll
    for (int off = 32; off > 0; off >>= 1)
        acc += __shfl_down(acc, off, 64);

    __shared__ float wsum[4];
    int lane = threadIdx.x & 63;
    int wave = threadIdx.x >> 6;
    if (lane == 0) wsum[wave] = acc;
    __syncthreads();
    if (threadIdx.x == 0) {
        partial[blockIdx.x] = wsum[0] + wsum[1] + wsum[2] + wsum[3];
    }
}

__global__ __launch_bounds__(256) void kp_final_kernel(
    const float* __restrict__ partial,
    float* __restrict__ result,
    int n)
{
    float acc = 0.0f;
    for (int i = threadIdx.x; i < n; i += 256)
        acc += partial[i];

    #pragma unroll
    for (int off = 32; off > 0; off >>= 1)
        acc += __shfl_down(acc, off, 64);

    __shared__ float wsum[4];
    int lane = threadIdx.x & 63;
    int wave = threadIdx.x >> 6;
    if (lane == 0) wsum[wave] = acc;
    __syncthreads();
    if (threadIdx.x == 0) {
        result[0] = (wsum[0] + wsum[1] + wsum[2] + wsum[3]) * (1.0f / (float)KP_B);
    }
}

extern "C" void kernel_launch(void* const* d_in, const int* in_sizes, int n_in,
                              void* d_out, int out_size, void* d_ws, size_t ws_size,
                              hipStream_t stream)
{
    const float4* out4 = (const float4*)d_in[0];
    const float4* tgt4 = (const float4*)d_in[1];
    float* result = (float*)d_out;
    float* partial = (float*)d_ws;

    const int n_floats = in_sizes[0];          // 8192*2048*2 = 33,554,432
    const int n4 = n_floats / 4;               // 8,388,608 float4 pairs

    const int block = 256;
    const int grid = 2048;                     // 8 blocks/CU, 16 f4/thread

    kp_partial_kernel<<<grid, block, 0, stream>>>(out4, tgt4, partial, n4);
    kp_final_kernel<<<1, block, 0, stream>>>(partial, result, grid);
}